// Round 6
// baseline (177.654 us; speedup 1.0000x reference)
//
#include <hip/hip_runtime.h>
#include <hip/hip_bf16.h>

// Problem constants (B, T, C, HS) = (4, 4096, 64, 64)
#define B_ 4
#define T_ 4096
#define UPB 4160      // units per batch: sum_i nkt_i, nkt_i = i/2+1, i<128
#define NB 256        // stream-K blocks per batch (grid = 4*NB = 1024)
#define SLOTS 5       // max blocks overlapping one q-tile: ceil(64/16.25)+1

typedef _Float16 half_t;
typedef __attribute__((ext_vector_type(8))) _Float16 half8;
typedef __attribute__((ext_vector_type(8))) short short8;
typedef __attribute__((ext_vector_type(4))) float f32x4;
typedef unsigned short ushort_t;
typedef unsigned int uint32;

__device__ __forceinline__ ushort_t h_bits(float f) {
    half_t h = (half_t)f;
    return __builtin_bit_cast(unsigned short, h);
}
__device__ __forceinline__ float f_of_h(ushort_t u) {
    half_t h = __builtin_bit_cast(half_t, u);
    return (float)h;
}
// 16-lane max-reduce on the VALU (DPP row = 16 lanes), avoiding the LDS pipe.
template <int CTRL>
__device__ __forceinline__ float dpp_fmax(float x) {
    int xi = __builtin_bit_cast(int, x);
    int yi = __builtin_amdgcn_update_dpp(xi, xi, CTRL, 0xF, 0xF, false);
    return fmaxf(x, __builtin_bit_cast(float, yi));
}
__device__ __forceinline__ float red16_fmax(float x) {
    x = dpp_fmax<0xB1>(x);    // quad_perm xor1
    x = dpp_fmax<0x4E>(x);    // quad_perm xor2
    x = dpp_fmax<0x141>(x);   // row_half_mirror
    x = dpp_fmax<0x140>(x);   // row_mirror
    return x;
}

// ---------------------------------------------------------------------------
// Kernel 1: QKV projection via fp16 MFMA; writes SPLIT fp16 Q,K (hi+residual)
// and fp16 V^T. Q pre-scaled by sqrt(C)*log2(e).
// ---------------------------------------------------------------------------
__global__ __launch_bounds__(256) void qkv_proj(
    const float* __restrict__ x, const float* __restrict__ Wq,
    const float* __restrict__ Wk, const float* __restrict__ Wv,
    half_t* __restrict__ Qh, half_t* __restrict__ Ql,
    half_t* __restrict__ Kh, half_t* __restrict__ Kl,
    half_t* __restrict__ Vt)
{
    __shared__ float Ws[3][64][65];
    const int tid = threadIdx.x;
    {
        const float* Wp[3] = {Wq, Wk, Wv};
        for (int mm = 0; mm < 3; ++mm)
            for (int ii = tid; ii < 4096; ii += 256)
                Ws[mm][ii >> 6][ii & 63] = Wp[mm][ii];
    }
    __syncthreads();

    const int w = tid >> 6, lane = tid & 63;
    const int l16 = lane & 15, g = lane >> 4;
    const int R0 = blockIdx.x * 32 + 16 * (w & 1);
    const int h = w >> 1;

    // x A-fragments split hi/lo (row=l16, k=cc*32+8g+j) for exact projection
    half8 ah[2], al[2];
#pragma unroll
    for (int cc = 0; cc < 2; ++cc) {
        const float* xp = x + (size_t)(R0 + l16) * 64 + cc * 32 + 8 * g;
        float4 v0 = *(const float4*)xp;
        float4 v1 = *(const float4*)(xp + 4);
        float xv[8] = {v0.x, v0.y, v0.z, v0.w, v1.x, v1.y, v1.z, v1.w};
#pragma unroll
        for (int jj = 0; jj < 8; ++jj) {
            half_t hh = (half_t)xv[jj];
            ah[cc][jj] = hh;
            al[cc][jj] = (half_t)(xv[jj] - (float)hh);
        }
    }

    const float QS = 11.541560327111707f;  // sqrt(64) * log2(e)
#pragma unroll
    for (int u6 = 0; u6 < 6; ++u6) {
        const int u = h * 6 + u6;
        const int mm = u >> 2, ct = u & 3;
        f32x4 d = (f32x4){0.f, 0.f, 0.f, 0.f};
#pragma unroll
        for (int cc = 0; cc < 2; ++cc) {
            half8 bh, bl;
#pragma unroll
            for (int jj = 0; jj < 8; ++jj) {
                float wv = Ws[mm][cc * 32 + 8 * g + jj][ct * 16 + l16];
                half_t hh = (half_t)wv;
                bh[jj] = hh;
                bl[jj] = (half_t)(wv - (float)hh);
            }
            d = __builtin_amdgcn_mfma_f32_16x16x32_f16(ah[cc], bh, d, 0, 0, 0);
            d = __builtin_amdgcn_mfma_f32_16x16x32_f16(ah[cc], bl, d, 0, 0, 0);
            d = __builtin_amdgcn_mfma_f32_16x16x32_f16(al[cc], bh, d, 0, 0, 0);
        }
        const int col = ct * 16 + l16;   // C/D: col=l16, row=4g+reg
        if (mm == 0) {
#pragma unroll
            for (int r = 0; r < 4; ++r) {
                float v = d[r] * QS;
                half_t hh = (half_t)v;
                Qh[(size_t)(R0 + 4 * g + r) * 64 + col] = hh;
                Ql[(size_t)(R0 + 4 * g + r) * 64 + col] = (half_t)(v - (float)hh);
            }
        } else if (mm == 1) {
#pragma unroll
            for (int r = 0; r < 4; ++r) {
                float v = d[r];
                half_t hh = (half_t)v;
                Kh[(size_t)(R0 + 4 * g + r) * 64 + col] = hh;
                Kl[(size_t)(R0 + 4 * g + r) * 64 + col] = (half_t)(v - (float)hh);
            }
        } else {
            const int bb = R0 >> 12;
            const int t0 = (R0 & (T_ - 1)) + 4 * g;
            uint2 pk;
            pk.x = (uint32)h_bits(d[0]) | ((uint32)h_bits(d[1]) << 16);
            pk.y = (uint32)h_bits(d[2]) | ((uint32)h_bits(d[3]) << 16);
            *(uint2*)(Vt + ((size_t)(bb * 64 + col)) * T_ + t0) = pk;
        }
    }
}

// ---------------------------------------------------------------------------
// Kernel 2: block-granular stream-K flash attention with XCD pinning.
// bid -> xcd = bid&7 -> batch b = xcd>>1 (each batch pinned to 2 XCDs so its
// ~2.5MB Q/K/V set stays L2-resident). Block rb (0..NB-1 within batch) owns
// units [65*rb/4, 65*(rb+1)/4) of the batch's 4160 (q-tile, kt) units.
// Within a run: wave wv -> su = wv&1 (16-row subtile), kt parity = wv>>1.
// End of run: LDS merge; full-tile runs write out directly, else flush
// one partial per (tile, block) to PACC/PML.
// ---------------------------------------------------------------------------
__global__ __launch_bounds__(256, 4) void flash_sk(
    const half_t* __restrict__ Qh, const half_t* __restrict__ Ql,
    const half_t* __restrict__ Kh, const half_t* __restrict__ Kl,
    const half_t* __restrict__ Vt,
    ushort_t* __restrict__ PACC, float* __restrict__ PML,
    float* __restrict__ out)
{
    __shared__ __align__(16) ushort_t Pb[4][16][72];  // per-wave P buffer
    __shared__ float mrgF[2][64][24];                 // [su][lane][m4,l4,acc16]

    const int tid = threadIdx.x;
    const int wv = tid >> 6;
    const int lane = tid & 63;
    const int l16 = lane & 15, g = lane >> 4;
    const int su = wv & 1, par = wv >> 1;

    const int bid = blockIdx.x;
    const int xcd = bid & 7;
    const int b = xcd >> 1;
    const int rb = ((bid >> 3) << 1) + (xcd & 1);    // 0..NB-1 within batch

    half8 ones;
#pragma unroll
    for (int jj = 0; jj < 8; ++jj) ones[jj] = (half_t)1.0f;

    int u = (65 * rb) >> 2;                  // = floor(UPB*rb/NB)
    const int uEnd = (65 * (rb + 1)) >> 2;

    while (u < uEnd) {
        // ---- decode unit u -> (q-tile i, first kt) ----
        const int r = u;
        int t = (int)sqrtf((float)r);
        while ((t + 1) * (t + 1) <= r) ++t;
        while (t * t > r) --t;
        int i, kt0;
        if (r < t * t + t) { i = 2 * t - 1; kt0 = r - t * t; }
        else               { i = 2 * t;     kt0 = r - t * t - t; }
        const int nkt = (i >> 1) + 1;
        const int q0 = i * 32;
        const int rem = nkt - kt0;
        const int avail = uEnd - u;
        const int cnt = (rem < avail) ? rem : avail;

        // ---- Q fragments (this wave's 16-row subtile), split hi/lo ----
        half8 aQh[2], aQl[2];
        {
            const size_t qb = ((size_t)(b * T_ + q0 + su * 16 + l16)) * 64;
#pragma unroll
            for (int cc = 0; cc < 2; ++cc) {
                aQh[cc] = *(const half8*)(Qh + qb + cc * 32 + 8 * g);
                aQl[cc] = *(const half8*)(Ql + qb + cc * 32 + 8 * g);
            }
        }

        float m[4], lsum[4];
        f32x4 acc[4];
#pragma unroll
        for (int rr = 0; rr < 4; ++rr) { m[rr] = -__builtin_inff(); lsum[rr] = 0.f; }
#pragma unroll
        for (int hs = 0; hs < 4; ++hs) acc[hs] = (f32x4){0.f, 0.f, 0.f, 0.f};

        for (int e = par; e < cnt; e += 2) {
            const int kt = kt0 + e;
            const size_t kb = ((size_t)(b * T_ + kt * 64)) * 64;
            f32x4 sc[4];
            // ---- QK^T: split fp16 (hi*hi + hi*lo + lo*hi), from L2 ----
            __builtin_amdgcn_s_setprio(1);
#pragma unroll
            for (int ks = 0; ks < 4; ++ks) {
                f32x4 a = (f32x4){0.f, 0.f, 0.f, 0.f};
#pragma unroll
                for (int cc = 0; cc < 2; ++cc) {
                    const size_t ko = kb + ((size_t)(ks * 16 + l16)) * 64 + cc * 32 + 8 * g;
                    half8 bh = *(const half8*)(Kh + ko);
                    half8 bl = *(const half8*)(Kl + ko);
                    a = __builtin_amdgcn_mfma_f32_16x16x32_f16(aQh[cc], bh, a, 0, 0, 0);
                    a = __builtin_amdgcn_mfma_f32_16x16x32_f16(aQh[cc], bl, a, 0, 0, 0);
                    a = __builtin_amdgcn_mfma_f32_16x16x32_f16(aQl[cc], bh, a, 0, 0, 0);
                }
                sc[ks] = a;
            }
            __builtin_amdgcn_s_setprio(0);
            // ---- causal mask (only diagonal tile crosses) ----
            if (kt == nkt - 1) {
#pragma unroll
                for (int ks = 0; ks < 4; ++ks)
#pragma unroll
                    for (int rr = 0; rr < 4; ++rr) {
                        int key = kt * 64 + ks * 16 + l16;
                        int row = q0 + su * 16 + 4 * g + rr;
                        if (key > row) sc[ks][rr] = -__builtin_inff();
                    }
            }
            // ---- online softmax: DPP row-max, exact defer-rescale ----
            float mt[4];
#pragma unroll
            for (int rr = 0; rr < 4; ++rr) {
                float tmx = fmaxf(fmaxf(sc[0][rr], sc[1][rr]),
                                  fmaxf(sc[2][rr], sc[3][rr]));
                mt[rr] = red16_fmax(tmx);
            }
            float alv[4];
            bool grow = (mt[0] > m[0]) | (mt[1] > m[1]) |
                        (mt[2] > m[2]) | (mt[3] > m[3]);
            if (__ballot(grow)) {
#pragma unroll
                for (int rr = 0; rr < 4; ++rr) {
                    float mn = fmaxf(m[rr], mt[rr]);
                    alv[rr] = exp2f(m[rr] - mn);   // -inf -> 0 on first tile
                    m[rr] = mn;
                }
#pragma unroll
                for (int hs = 0; hs < 4; ++hs)
#pragma unroll
                    for (int rr = 0; rr < 4; ++rr) acc[hs][rr] *= alv[rr];
            } else {
#pragma unroll
                for (int rr = 0; rr < 4; ++rr) alv[rr] = 1.f;
            }
#pragma unroll
            for (int ks = 0; ks < 4; ++ks)
#pragma unroll
                for (int rr = 0; rr < 4; ++rr) {
                    float pv = exp2f(sc[ks][rr] - m[rr]);
                    Pb[wv][4 * g + rr][ks * 16 + l16] = h_bits(pv);
                }
            // ---- row-sum via ones-MFMA + PV ----
            f32x4 rs = (f32x4){0.f, 0.f, 0.f, 0.f};
            __builtin_amdgcn_s_setprio(1);
#pragma unroll
            for (int cc = 0; cc < 2; ++cc) {
                half8 ap = *(const half8*)&Pb[wv][l16][cc * 32 + 8 * g];
                rs = __builtin_amdgcn_mfma_f32_16x16x32_f16(ap, ones, rs, 0, 0, 0);
#pragma unroll
                for (int hs = 0; hs < 4; ++hs) {
                    half8 bv = *(const half8*)(Vt + ((size_t)(b * 64 + hs * 16 + l16)) * T_
                                               + kt * 64 + cc * 32 + 8 * g);
                    acc[hs] = __builtin_amdgcn_mfma_f32_16x16x32_f16(ap, bv, acc[hs], 0, 0, 0);
                }
            }
            __builtin_amdgcn_s_setprio(0);
#pragma unroll
            for (int rr = 0; rr < 4; ++rr)
                lsum[rr] = lsum[rr] * alv[rr] + rs[rr];
        }

        // ---- in-block merge: waves 2,3 publish; waves 0,1 combine ----
        if (par == 1) {
            float* mp = &mrgF[su][lane][0];
#pragma unroll
            for (int rr = 0; rr < 4; ++rr) { mp[rr] = m[rr]; mp[4 + rr] = lsum[rr]; }
#pragma unroll
            for (int hs = 0; hs < 4; ++hs)
#pragma unroll
                for (int rr = 0; rr < 4; ++rr) mp[8 + hs * 4 + rr] = acc[hs][rr];
        }
        __syncthreads();
        if (par == 0) {
            const float* mp = &mrgF[su][lane][0];
#pragma unroll
            for (int rr = 0; rr < 4; ++rr) {
                float m1 = mp[rr], l1 = mp[4 + rr];
                float mf = fmaxf(m[rr], m1);          // m[rr] finite (par0 ran)
                float a0 = exp2f(m[rr] - mf);
                float a1 = exp2f(m1 - mf);            // m1==-inf (idle) -> 0
                lsum[rr] = lsum[rr] * a0 + l1 * a1;
#pragma unroll
                for (int hs = 0; hs < 4; ++hs)
                    acc[hs][rr] = acc[hs][rr] * a0 + mp[8 + hs * 4 + rr] * a1;
                m[rr] = mf;
            }
            const bool full = (kt0 == 0) && (cnt == nkt);
            if (full) {
                // ---- whole tile computed here: write out directly ----
#pragma unroll
                for (int rr = 0; rr < 4; ++rr) {
                    float inv = 1.f / lsum[rr];
                    const size_t ob = ((size_t)(b * T_ + q0 + su * 16 + 4 * g + rr)) * 64;
#pragma unroll
                    for (int hs = 0; hs < 4; ++hs)
                        out[ob + hs * 16 + l16] = acc[hs][rr] * inv;
                }
            } else {
                // ---- flush one partial per (tile, block) ----
                const int mh = i >> 1;
                const int Si = (i & 1) ? (mh + 1) * (mh + 1) : mh * (mh + 1);
                const int rbf = (4 * Si + 3) / 65;    // first block owning tile i
                const int slot = rb - rbf;
                const int Tid = b * 128 + i;
                ushort_t* pa = PACC + ((size_t)(Tid * SLOTS + slot)) * 2048;
                float* pm = PML + ((size_t)(Tid * SLOTS + slot)) * 64;
#pragma unroll
                for (int hs = 0; hs < 4; ++hs)
#pragma unroll
                    for (int rr = 0; rr < 4; ++rr)
                        pa[(su * 16 + 4 * g + rr) * 64 + hs * 16 + l16] = h_bits(acc[hs][rr]);
                if (l16 == 0) {
#pragma unroll
                    for (int rr = 0; rr < 4; ++rr) {
                        const int row = su * 16 + 4 * g + rr;
                        pm[row * 2] = m[rr];
                        pm[row * 2 + 1] = lsum[rr];
                    }
                }
            }
        }
        __syncthreads();
        u += cnt;
    }
}

// ---------------------------------------------------------------------------
// Kernel 3: merge partials for tiles that were split across blocks.
// grid = 512 (one block per q-tile); single-block tiles already wrote out.
// ---------------------------------------------------------------------------
__global__ __launch_bounds__(256) void merge_k(
    const ushort_t* __restrict__ PACC, const float* __restrict__ PML,
    float* __restrict__ out)
{
    const int tid = threadIdx.x;
    const int Tid = blockIdx.x;
    const int b = Tid >> 7, i = Tid & 127;
    const int nkt = (i >> 1) + 1;
    const int mh = i >> 1;
    const int Si = (i & 1) ? (mh + 1) * (mh + 1) : mh * (mh + 1);
    const int rbf = (4 * Si + 3) / 65;
    const int rbl = (4 * (Si + nkt - 1) + 3) / 65;
    const int n = rbl - rbf + 1;
    if (n == 1) return;                       // covering block wrote out directly

    const int row = tid >> 3;
    const int c0 = (tid & 7) * 8;

    float mm = -__builtin_inff(), ll = 0.f;
    float ac[8];
#pragma unroll
    for (int k2 = 0; k2 < 8; ++k2) ac[k2] = 0.f;

    for (int p = 0; p < n; ++p) {
        const float* pm = PML + ((size_t)(Tid * SLOTS + p)) * 64 + row * 2;
        float m1 = pm[0], l1 = pm[1];
        short8 pv = *(const short8*)(PACC + ((size_t)(Tid * SLOTS + p)) * 2048 + row * 64 + c0);
        float mf = fmaxf(mm, m1);
        float a0 = exp2f(mm - mf), a1 = exp2f(m1 - mf);
        ll = ll * a0 + l1 * a1;
#pragma unroll
        for (int k2 = 0; k2 < 8; ++k2)
            ac[k2] = ac[k2] * a0 + f_of_h((ushort_t)pv[k2]) * a1;
        mm = mf;
    }
    float inv = 1.f / ll;
    float* op = out + ((size_t)(b * T_ + i * 32 + row)) * 64 + c0;
    float4 o0, o1;
    o0.x = ac[0] * inv; o0.y = ac[1] * inv; o0.z = ac[2] * inv; o0.w = ac[3] * inv;
    o1.x = ac[4] * inv; o1.y = ac[5] * inv; o1.z = ac[6] * inv; o1.w = ac[7] * inv;
    *(float4*)op = o0;
    *(float4*)(op + 4) = o1;
}

// ---------------------------------------------------------------------------
extern "C" void kernel_launch(void* const* d_in, const int* in_sizes, int n_in,
                              void* d_out, int out_size, void* d_ws, size_t ws_size,
                              hipStream_t stream) {
    const float* x  = (const float*)d_in[0];
    const float* Wq = (const float*)d_in[1];
    const float* Wk = (const float*)d_in[2];
    const float* Wv = (const float*)d_in[3];
    float* out = (float*)d_out;

    // ws carve: Qh,Ql,Kh,Kl,Vt (5 x 2MB fp16) | PACC 10.5MB | PML 0.64MB
    const size_t N = (size_t)B_ * T_ * 64;
    half_t* Qh = (half_t*)d_ws;
    half_t* Ql = Qh + N;
    half_t* Kh = Ql + N;
    half_t* Kl = Kh + N;
    half_t* Vt = Kl + N;
    ushort_t* PACC = (ushort_t*)(Vt + N);
    float* PML = (float*)(PACC + (size_t)512 * SLOTS * 2048);

    qkv_proj<<<512, 256, 0, stream>>>(x, Wq, Wk, Wv, Qh, Ql, Kh, Kl, Vt);
    flash_sk<<<4 * NB, 256, 0, stream>>>(Qh, Ql, Kh, Kl, Vt, PACC, PML, out);
    merge_k<<<512, 256, 0, stream>>>(PACC, PML, out);
}

// Round 7
// 131.422 us; speedup vs baseline: 1.3518x; 1.3518x over previous
//
#include <hip/hip_runtime.h>
#include <hip/hip_bf16.h>

// Problem constants (B, T, C, HS) = (4, 4096, 64, 64)
#define B_ 4
#define T_ 4096
#define UPB 4160      // units per batch: sum_i nkt_i, nkt_i = i/2+1, i<128

typedef _Float16 half_t;
typedef __attribute__((ext_vector_type(8))) _Float16 half8;
typedef __attribute__((ext_vector_type(8))) short short8;
typedef __attribute__((ext_vector_type(4))) float f32x4;
typedef unsigned short ushort_t;
typedef unsigned int uint32;

__device__ __forceinline__ ushort_t h_bits(float f) {
    half_t h = (half_t)f;
    return __builtin_bit_cast(unsigned short, h);
}
__device__ __forceinline__ float f_of_h(ushort_t u) {
    half_t h = __builtin_bit_cast(half_t, u);
    return (float)h;
}
// 16-lane max-reduce on the VALU (DPP row = 16 lanes), avoiding the LDS pipe.
template <int CTRL>
__device__ __forceinline__ float dpp_fmax(float x) {
    int xi = __builtin_bit_cast(int, x);
    int yi = __builtin_amdgcn_update_dpp(xi, xi, CTRL, 0xF, 0xF, false);
    return fmaxf(x, __builtin_bit_cast(float, yi));
}
__device__ __forceinline__ float red16_fmax(float x) {
    x = dpp_fmax<0xB1>(x);    // quad_perm xor1
    x = dpp_fmax<0x4E>(x);    // quad_perm xor2
    x = dpp_fmax<0x141>(x);   // row_half_mirror
    x = dpp_fmax<0x140>(x);   // row_mirror
    return x;
}

// Fragment-order layouts (all fp16), chosen so flash loads are base+lane*16B:
//   Q: Qf[(R>>4)][cc][lane][8]  where R = global q row, lane=((c>>3)&3)*16+(R&15), j=c&7
//      (R>>4 enumerates [b][tile i][su])
//   K: Kf[(R>>4)][cc][lane][8]  (R>>4 enumerates [b][kt][ks])   -- same formula
//   V: Vf[b][kt][hs][cc][lane][8], value V[t][h], lane=((t>>3)&3)*16+(h&15), j=t&7

// ---------------------------------------------------------------------------
// Kernel 1: QKV projection via split-fp16 MFMA, emitting fragment-order
// Q (hi/lo, pre-scaled by sqrt(C)*log2e), K (hi/lo), V. XCD-pinned per batch.
// ---------------------------------------------------------------------------
__global__ __launch_bounds__(256) void qkv_proj(
    const float* __restrict__ x, const float* __restrict__ Wq,
    const float* __restrict__ Wk, const float* __restrict__ Wv,
    half_t* __restrict__ Qfh, half_t* __restrict__ Qfl,
    half_t* __restrict__ Kfh, half_t* __restrict__ Kfl,
    half_t* __restrict__ Vf)
{
    __shared__ float Ws[3][64][65];
    const int tid = threadIdx.x;
    {
        const float* Wp[3] = {Wq, Wk, Wv};
        for (int mm = 0; mm < 3; ++mm)
            for (int ii = tid; ii < 4096; ii += 256)
                Ws[mm][ii >> 6][ii & 63] = Wp[mm][ii];
    }
    __syncthreads();

    const int w = tid >> 6, lane = tid & 63;
    const int l16 = lane & 15, g = lane >> 4;
    // XCD pinning: batch b -> xcds {2b, 2b+1}
    const int bid = blockIdx.x;
    const int xcd = bid & 7;
    const int bb = xcd >> 1;
    const int idx = ((bid >> 3) << 1) + (xcd & 1);        // 0..127
    const int R0 = bb * T_ + idx * 32 + 16 * (w & 1);     // global row base (mult of 16)
    const int h = w >> 1;

    // x A-fragments split hi/lo (row=l16, k=cc*32+8g+j)
    half8 ah[2], al[2];
#pragma unroll
    for (int cc = 0; cc < 2; ++cc) {
        const float* xp = x + (size_t)(R0 + l16) * 64 + cc * 32 + 8 * g;
        float4 v0 = *(const float4*)xp;
        float4 v1 = *(const float4*)(xp + 4);
        float xv[8] = {v0.x, v0.y, v0.z, v0.w, v1.x, v1.y, v1.z, v1.w};
#pragma unroll
        for (int jj = 0; jj < 8; ++jj) {
            half_t hh = (half_t)xv[jj];
            ah[cc][jj] = hh;
            al[cc][jj] = (half_t)(xv[jj] - (float)hh);
        }
    }

    const float QS = 11.541560327111707f;  // sqrt(64) * log2(e)
#pragma unroll
    for (int u6 = 0; u6 < 6; ++u6) {
        const int u = h * 6 + u6;
        const int mm = u >> 2, ct = u & 3;
        f32x4 d = (f32x4){0.f, 0.f, 0.f, 0.f};
#pragma unroll
        for (int cc = 0; cc < 2; ++cc) {
            half8 bh, bl;
#pragma unroll
            for (int jj = 0; jj < 8; ++jj) {
                float wv = Ws[mm][cc * 32 + 8 * g + jj][ct * 16 + l16];
                half_t hh = (half_t)wv;
                bh[jj] = hh;
                bl[jj] = (half_t)(wv - (float)hh);
            }
            d = __builtin_amdgcn_mfma_f32_16x16x32_f16(ah[cc], bh, d, 0, 0, 0);
            d = __builtin_amdgcn_mfma_f32_16x16x32_f16(ah[cc], bl, d, 0, 0, 0);
            d = __builtin_amdgcn_mfma_f32_16x16x32_f16(al[cc], bh, d, 0, 0, 0);
        }
        const int c = ct * 16 + l16;   // output column; C/D row = 4g+reg
        if (mm == 2) {
            // V fragment-order: thread's 4 values are consecutive j at one slot
            const int Rt0 = (R0 & (T_ - 1)) + 4 * g;      // t for r=0
            const int kt = Rt0 >> 6, cc2 = (Rt0 & 63) >> 5;
            const int lv = ((Rt0 >> 3) & 3) * 16 + (c & 15);
            const size_t base = ((((size_t)(bb * 64 + kt) * 4 + (c >> 4)) * 2 + cc2) * 64
                                 + lv) * 8 + (Rt0 & 7);
            uint2 pk;
            pk.x = (uint32)h_bits(d[0]) | ((uint32)h_bits(d[1]) << 16);
            pk.y = (uint32)h_bits(d[2]) | ((uint32)h_bits(d[3]) << 16);
            *(uint2*)(Vf + base) = pk;
        } else {
#pragma unroll
            for (int r = 0; r < 4; ++r) {
                const int R = R0 + 4 * g + r;
                const size_t fa = (((size_t)(R >> 4) * 2 + (c >> 5)) * 64
                                   + ((c >> 3) & 3) * 16 + (R & 15)) * 8 + (c & 7);
                if (mm == 0) {
                    float v = d[r] * QS;
                    half_t hh = (half_t)v;
                    Qfh[fa] = hh;
                    Qfl[fa] = (half_t)(v - (float)hh);
                } else {
                    float v = d[r];
                    half_t hh = (half_t)v;
                    Kfh[fa] = hh;
                    Kfl[fa] = (half_t)(v - (float)hh);
                }
            }
        }
    }
}

// ---------------------------------------------------------------------------
// Kernel 2: stream-K flash attention, independent dual-subtile waves
// (round-4 structure), fragment-order coalesced loads, XCD batch pinning,
// direct-write for fully-covered tiles, DPP max + ones-MFMA rowsum +
// exact defer-rescale, split-fp16 QK^T.
// ---------------------------------------------------------------------------
__global__ __launch_bounds__(256, 3) void flash_sk(
    const half_t* __restrict__ Qfh, const half_t* __restrict__ Qfl,
    const half_t* __restrict__ Kfh, const half_t* __restrict__ Kfl,
    const half_t* __restrict__ Vf,
    ushort_t* __restrict__ PACC, float* __restrict__ PML,
    float* __restrict__ out, const int S, const int SLOTS)
{
    __shared__ __align__(16) ushort_t Pb[4][2][16][72];

    const int tid = threadIdx.x;
    const int wv = tid >> 6;
    const int lane = tid & 63;
    const int l16 = lane & 15, g = lane >> 4;

    // XCD pinning: batch b -> xcds {2b, 2b+1}; W = within-batch wave id
    const int bid = blockIdx.x;
    const int xcd = bid & 7;
    const int b = xcd >> 1;
    const int rbb = ((bid >> 3) << 1) + (xcd & 1);
    const int W = rbb * 4 + wv;                 // 0 .. 64*S-1

    half8 ones;
#pragma unroll
    for (int jj = 0; jj < 8; ++jj) ones[jj] = (half_t)1.0f;

    int u = (65 * W) / S;                       // within-batch unit range
    const int uEnd = (65 * (W + 1)) / S;

    while (u < uEnd) {
        // ---- decode unit u -> (q-tile i, first kt) ----
        const int r = u;
        int t = (int)sqrtf((float)r);
        while ((t + 1) * (t + 1) <= r) ++t;
        while (t * t > r) --t;
        int i, kt0;
        if (r < t * t + t) { i = 2 * t - 1; kt0 = r - t * t; }
        else               { i = 2 * t;     kt0 = r - t * t - t; }
        const int nkt = (i >> 1) + 1;
        const int q0 = i * 32;
        const int rem = nkt - kt0;
        const int avail = uEnd - u;
        const int run = (rem < avail) ? rem : avail;

        // ---- Q fragments, both subtiles, coalesced (base + lane*16B) ----
        half8 aQh[2][2], aQl[2][2];
#pragma unroll
        for (int su = 0; su < 2; ++su)
#pragma unroll
            for (int cc = 0; cc < 2; ++cc) {
                const size_t qo = ((((size_t)((b * 128 + i) * 2 + su)) * 2 + cc) * 64
                                   + lane) * 8;
                aQh[su][cc] = *(const half8*)(Qfh + qo);
                aQl[su][cc] = *(const half8*)(Qfl + qo);
            }

        float m[2][4], lsum[2][4];
        f32x4 acc[2][4];
#pragma unroll
        for (int su = 0; su < 2; ++su)
#pragma unroll
            for (int rr = 0; rr < 4; ++rr) { m[su][rr] = -__builtin_inff(); lsum[su][rr] = 0.f; }
#pragma unroll
        for (int su = 0; su < 2; ++su)
#pragma unroll
            for (int hs = 0; hs < 4; ++hs) acc[su][hs] = (f32x4){0.f, 0.f, 0.f, 0.f};

        for (int e = 0; e < run; ++e) {
            const int kt = kt0 + e;
            const size_t tb = (size_t)(b * 64 + kt) * 4;
            f32x4 sc[2][4];
            // ---- QK^T: split fp16, coalesced fragment loads ----
            __builtin_amdgcn_s_setprio(1);
#pragma unroll
            for (int ks = 0; ks < 4; ++ks) {
                f32x4 a0 = (f32x4){0.f, 0.f, 0.f, 0.f};
                f32x4 a1 = (f32x4){0.f, 0.f, 0.f, 0.f};
#pragma unroll
                for (int cc = 0; cc < 2; ++cc) {
                    const size_t ko = ((tb + ks) * 2 + cc) * 512 + lane * 8;
                    half8 bh = *(const half8*)(Kfh + ko);
                    half8 bl = *(const half8*)(Kfl + ko);
                    a0 = __builtin_amdgcn_mfma_f32_16x16x32_f16(aQh[0][cc], bh, a0, 0, 0, 0);
                    a0 = __builtin_amdgcn_mfma_f32_16x16x32_f16(aQh[0][cc], bl, a0, 0, 0, 0);
                    a0 = __builtin_amdgcn_mfma_f32_16x16x32_f16(aQl[0][cc], bh, a0, 0, 0, 0);
                    a1 = __builtin_amdgcn_mfma_f32_16x16x32_f16(aQh[1][cc], bh, a1, 0, 0, 0);
                    a1 = __builtin_amdgcn_mfma_f32_16x16x32_f16(aQh[1][cc], bl, a1, 0, 0, 0);
                    a1 = __builtin_amdgcn_mfma_f32_16x16x32_f16(aQl[1][cc], bh, a1, 0, 0, 0);
                }
                sc[0][ks] = a0; sc[1][ks] = a1;
            }
            __builtin_amdgcn_s_setprio(0);
            // ---- causal mask (only diagonal tile crosses) ----
            if (kt == nkt - 1) {
#pragma unroll
                for (int su = 0; su < 2; ++su)
#pragma unroll
                    for (int ks = 0; ks < 4; ++ks)
#pragma unroll
                        for (int rr = 0; rr < 4; ++rr) {
                            int key = kt * 64 + ks * 16 + l16;
                            int row = q0 + su * 16 + 4 * g + rr;
                            if (key > row) sc[su][ks][rr] = -__builtin_inff();
                        }
            }
            // ---- online softmax: DPP row-max + exact defer-rescale ----
            float mt[2][4];
#pragma unroll
            for (int su = 0; su < 2; ++su)
#pragma unroll
                for (int rr = 0; rr < 4; ++rr) {
                    float tmx = fmaxf(fmaxf(sc[su][0][rr], sc[su][1][rr]),
                                      fmaxf(sc[su][2][rr], sc[su][3][rr]));
                    mt[su][rr] = red16_fmax(tmx);
                }
            float alv[2][4];
            bool grow = false;
#pragma unroll
            for (int su = 0; su < 2; ++su)
#pragma unroll
                for (int rr = 0; rr < 4; ++rr) grow |= (mt[su][rr] > m[su][rr]);
            if (__ballot(grow)) {
#pragma unroll
                for (int su = 0; su < 2; ++su)
#pragma unroll
                    for (int rr = 0; rr < 4; ++rr) {
                        float mn = fmaxf(m[su][rr], mt[su][rr]);
                        alv[su][rr] = exp2f(m[su][rr] - mn);   // -inf -> 0 first tile
                        m[su][rr] = mn;
                    }
#pragma unroll
                for (int su = 0; su < 2; ++su)
#pragma unroll
                    for (int hs = 0; hs < 4; ++hs)
#pragma unroll
                        for (int rr = 0; rr < 4; ++rr) acc[su][hs][rr] *= alv[su][rr];
            } else {
#pragma unroll
                for (int su = 0; su < 2; ++su)
#pragma unroll
                    for (int rr = 0; rr < 4; ++rr) alv[su][rr] = 1.f;
            }
#pragma unroll
            for (int su = 0; su < 2; ++su)
#pragma unroll
                for (int ks = 0; ks < 4; ++ks)
#pragma unroll
                    for (int rr = 0; rr < 4; ++rr) {
                        float pv = exp2f(sc[su][ks][rr] - m[su][rr]);
                        Pb[wv][su][4 * g + rr][ks * 16 + l16] = h_bits(pv);
                    }
            // ---- rowsum via ones-MFMA + PV (coalesced V fragments) ----
            f32x4 rs0 = (f32x4){0.f, 0.f, 0.f, 0.f};
            f32x4 rs1 = (f32x4){0.f, 0.f, 0.f, 0.f};
            __builtin_amdgcn_s_setprio(1);
#pragma unroll
            for (int cc = 0; cc < 2; ++cc) {
                half8 ap0 = *(const half8*)&Pb[wv][0][l16][cc * 32 + 8 * g];
                half8 ap1 = *(const half8*)&Pb[wv][1][l16][cc * 32 + 8 * g];
                rs0 = __builtin_amdgcn_mfma_f32_16x16x32_f16(ap0, ones, rs0, 0, 0, 0);
                rs1 = __builtin_amdgcn_mfma_f32_16x16x32_f16(ap1, ones, rs1, 0, 0, 0);
#pragma unroll
                for (int hs = 0; hs < 4; ++hs) {
                    half8 bv = *(const half8*)(Vf + ((tb + hs) * 2 + cc) * 512 + lane * 8);
                    acc[0][hs] = __builtin_amdgcn_mfma_f32_16x16x32_f16(ap0, bv, acc[0][hs], 0, 0, 0);
                    acc[1][hs] = __builtin_amdgcn_mfma_f32_16x16x32_f16(ap1, bv, acc[1][hs], 0, 0, 0);
                }
            }
            __builtin_amdgcn_s_setprio(0);
#pragma unroll
            for (int rr = 0; rr < 4; ++rr) {
                lsum[0][rr] = lsum[0][rr] * alv[0][rr] + rs0[rr];
                lsum[1][rr] = lsum[1][rr] * alv[1][rr] + rs1[rr];
            }
        }

        const bool full = (kt0 == 0) && (run == nkt);
        if (full) {
            // ---- whole tile computed by this wave: write out directly ----
#pragma unroll
            for (int su = 0; su < 2; ++su)
#pragma unroll
                for (int rr = 0; rr < 4; ++rr) {
                    float inv = 1.f / lsum[su][rr];
                    const size_t ob = ((size_t)(b * T_ + q0 + su * 16 + 4 * g + rr)) * 64;
#pragma unroll
                    for (int hs = 0; hs < 4; ++hs)
                        out[ob + hs * 16 + l16] = acc[su][hs][rr] * inv;
                }
        } else {
            // ---- flush partial (m,l fp32; acc fp16) ----
            const int mh = i >> 1;
            const int Si = (i & 1) ? (mh + 1) * (mh + 1) : mh * (mh + 1);
            const int Wf = (S * Si + S - 1) / 65;
            const int slot = W - Wf;
            const int Tid = b * 128 + i;
            ushort_t* pa = PACC + ((size_t)(Tid * SLOTS + slot)) * 2048;
            float* pm = PML + ((size_t)(Tid * SLOTS + slot)) * 64;
#pragma unroll
            for (int su = 0; su < 2; ++su)
#pragma unroll
                for (int hs = 0; hs < 4; ++hs)
#pragma unroll
                    for (int rr = 0; rr < 4; ++rr)
                        pa[(su * 16 + 4 * g + rr) * 64 + hs * 16 + l16] = h_bits(acc[su][hs][rr]);
            if (l16 == 0) {
#pragma unroll
                for (int su = 0; su < 2; ++su)
#pragma unroll
                    for (int rr = 0; rr < 4; ++rr) {
                        const int row = su * 16 + 4 * g + rr;
                        pm[row * 2] = m[su][rr];
                        pm[row * 2 + 1] = lsum[su][rr];
                    }
            }
        }
        u += run;
    }
}

// ---------------------------------------------------------------------------
// Kernel 3: merge partials for tiles split across waves (n>1 only).
// XCD-pinned to the batch's xcd pair.
// ---------------------------------------------------------------------------
__global__ __launch_bounds__(256) void merge_k(
    const ushort_t* __restrict__ PACC, const float* __restrict__ PML,
    float* __restrict__ out, const int S, const int SLOTS)
{
    const int tid = threadIdx.x;
    const int bid = blockIdx.x;
    const int xcd = bid & 7;
    const int b = xcd >> 1;
    const int i = ((bid >> 3) << 1) + (xcd & 1);       // 0..127
    const int nkt = (i >> 1) + 1;
    const int mh = i >> 1;
    const int Si = (i & 1) ? (mh + 1) * (mh + 1) : mh * (mh + 1);
    const int Wf = (S * Si + S - 1) / 65;
    const int Wl = (S * (Si + nkt - 1) + S - 1) / 65;
    const int n = Wl - Wf + 1;
    if (n == 1) return;                    // covering wave wrote out directly

    const int Tid = b * 128 + i;
    const int row = tid >> 3;
    const int c0 = (tid & 7) * 8;

    float mm = -__builtin_inff(), ll = 0.f;
    float ac[8];
#pragma unroll
    for (int k2 = 0; k2 < 8; ++k2) ac[k2] = 0.f;

    for (int p = 0; p < n; ++p) {
        const float* pm = PML + ((size_t)(Tid * SLOTS + p)) * 64 + row * 2;
        float m1 = pm[0], l1 = pm[1];
        short8 pv = *(const short8*)(PACC + ((size_t)(Tid * SLOTS + p)) * 2048 + row * 64 + c0);
        float mf = fmaxf(mm, m1);
        float a0 = exp2f(mm - mf), a1 = exp2f(m1 - mf);
        ll = ll * a0 + l1 * a1;
#pragma unroll
        for (int k2 = 0; k2 < 8; ++k2)
            ac[k2] = ac[k2] * a0 + f_of_h((ushort_t)pv[k2]) * a1;
        mm = mf;
    }
    float inv = 1.f / ll;
    float* op = out + ((size_t)(b * T_ + i * 32 + row)) * 64 + c0;
    float4 o0, o1;
    o0.x = ac[0] * inv; o0.y = ac[1] * inv; o0.z = ac[2] * inv; o0.w = ac[3] * inv;
    o1.x = ac[4] * inv; o1.y = ac[5] * inv; o1.z = ac[6] * inv; o1.w = ac[7] * inv;
    *(float4*)op = o0;
    *(float4*)(op + 4) = o1;
}

// ---------------------------------------------------------------------------
extern "C" void kernel_launch(void* const* d_in, const int* in_sizes, int n_in,
                              void* d_out, int out_size, void* d_ws, size_t ws_size,
                              hipStream_t stream) {
    const float* x  = (const float*)d_in[0];
    const float* Wq = (const float*)d_in[1];
    const float* Wk = (const float*)d_in[2];
    const float* Wv = (const float*)d_in[3];
    float* out = (float*)d_out;

    // ws carve: Qfh,Qfl,Kfh,Kfl,Vf (5 x 2MB fp16, fragment order) | PACC | PML
    const size_t N = (size_t)B_ * T_ * 64;
    half_t* Qfh = (half_t*)d_ws;
    half_t* Qfl = Qfh + N;
    half_t* Kfh = Qfl + N;
    half_t* Kfl = Kfh + N;
    half_t* Vf  = Kfl + N;
    ushort_t* PACC = (ushort_t*)(Vf + N);

    const size_t base = 5 * N * sizeof(half_t);                              // 10.5 MB
    const size_t need12 = base + (size_t)512 * 13 * (2048 * 2 + 256);        // ~39.5 MB

    qkv_proj<<<512, 256, 0, stream>>>(x, Wq, Wk, Wv, Qfh, Qfl, Kfh, Kfl, Vf);

    if (ws_size >= need12) {
        const int S = 12, SLOTS = 13;                 // 768 blocks, 3/CU
        float* PML = (float*)(PACC + (size_t)512 * SLOTS * 2048);
        flash_sk<<<768, 256, 0, stream>>>(Qfh, Qfl, Kfh, Kfl, Vf, PACC, PML, out, S, SLOTS);
        merge_k<<<512, 256, 0, stream>>>(PACC, PML, out, S, SLOTS);
    } else {
        const int S = 8, SLOTS = 9;                   // 512 blocks (ws >= 30.6MB per round-4 evidence)
        float* PML = (float*)(PACC + (size_t)512 * SLOTS * 2048);
        flash_sk<<<512, 256, 0, stream>>>(Qfh, Qfl, Kfh, Kfl, Vf, PACC, PML, out, S, SLOTS);
        merge_k<<<512, 256, 0, stream>>>(PACC, PML, out, S, SLOTS);
    }
}